// Round 3
// baseline (42.460 us; speedup 1.0000x reference)
//
#include <hip/hip_runtime.h>
#include <hip/hip_bf16.h>
#include <math.h>

// Problem constants: B=1, C=256, H=W=50, N=256 boxes, OUT=7
#define RC    256
#define RH    50
#define RW    50
#define RN    256
#define ROUT  7
#define NBINS 49
#define HW    (RH * RW)

// ---------- LDS-tiled transpose: feat[C][HW] -> featT[HW][C] ----------
__global__ void __launch_bounds__(256)
transpose_kernel(const float* __restrict__ feat, float* __restrict__ featT) {
    __shared__ float tile[64][65];
    int ct = blockIdx.x & 3;        // 4 c-tiles (256/64)
    int ht = blockIdx.x >> 2;       // 40 hw-tiles (ceil(2500/64))
    int c0 = ct * 64;
    int h0 = ht * 64;
    int col  = threadIdx.x & 63;
    int row4 = threadIdx.x >> 6;    // 0..3

    #pragma unroll
    for (int i = 0; i < 16; ++i) {
        int r  = row4 + 4 * i;              // channel-row within tile
        int hw = h0 + col;
        if (hw < HW)
            tile[r][col] = feat[(c0 + r) * HW + hw];   // coalesced along hw
    }
    __syncthreads();
    #pragma unroll
    for (int i = 0; i < 16; ++i) {
        int r  = row4 + 4 * i;              // hw-row within tile
        int hw = h0 + r;
        if (hw < HW)
            featT[hw * RC + c0 + col] = tile[col][r];  // coalesced along c
    }
}

// ---------- pool: one block per (box, 64-channel slice) ----------
__global__ void __launch_bounds__(256)
pool_kernel(const float* __restrict__ featT,
            const float* __restrict__ boxes,
            const int* __restrict__ image_size_p,
            float* __restrict__ out) {
    __shared__ float lds[NBINS * 65];
    int n    = blockIdx.x >> 2;
    int coff = (blockIdx.x & 3) * 64;
    int lane = threadIdx.x & 63;
    int wv   = threadIdx.x >> 6;    // 0..3

    float im = (float)(*image_size_p);
    float scale_w = (float)RW / im;
    float scale_h = (float)RH / im;

    float bx = boxes[n * 4 + 0];
    float by = boxes[n * 4 + 1];
    float bw = boxes[n * 4 + 2];
    float bh = boxes[n * 4 + 3];
    bool bad = (bw <= 0.0f) || (bh <= 0.0f);

    float x1f = (bad ? 0.25f * im : bx) * scale_w;
    float x2f = (bad ? 0.75f * im : bx + bw) * scale_w;
    float y1f = (bad ? 0.25f * im : by) * scale_h;
    float y2f = (bad ? 0.75f * im : by + bh) * scale_h;

    int x1 = max(0, (int)x1f);
    int y1 = max(0, (int)y1f);
    int x2 = min(RW, (int)x2f + 1);
    int y2 = min(RH, (int)y2f + 1);
    if (x2 <= x1 + 1) x2 = min(x1 + 2, RW);
    if (y2 <= y1 + 1) y2 = min(y1 + 2, RH);
    x1 = min(max(x1, 0), RW - 2);
    y1 = min(max(y1, 0), RH - 2);
    x2 = max(x1 + 1, min(x2, RW));
    y2 = max(y1 + 1, min(y2, RH));

    int szx = x2 - x1;
    int szy = y2 - y1;

    const float* __restrict__ base = featT + coff + lane;

    for (int bin = wv; bin < NBINS; bin += 4) {
        int ky = bin / ROUT;
        int kx = bin - ky * ROUT;
        int sx = x1 + (kx * szx) / ROUT;
        int ex = x1 + ((kx + 1) * szx + ROUT - 1) / ROUT;
        int sy = y1 + (ky * szy) / ROUT;
        int ey = y1 + ((ky + 1) * szy + ROUT - 1) / ROUT;

        float m = -INFINITY;
        for (int y = sy; y < ey; ++y) {
            const float* __restrict__ rp = base + (y * RW) * RC;
            int x = sx;
            for (; x + 2 <= ex; x += 2) {      // 2 loads in flight
                float v0 = rp[x * RC];
                float v1 = rp[(x + 1) * RC];
                m = fmaxf(m, fmaxf(v0, v1));
            }
            if (x < ex) m = fmaxf(m, rp[x * RC]);
        }
        lds[bin * 65 + lane] = m;              // bank-conflict-free
    }
    __syncthreads();

    // coalesced writeout: 3136 consecutive floats per block
    int obase = n * (RC * NBINS) + coff * NBINS;
    for (int e = threadIdx.x; e < 64 * NBINS; e += 256) {
        unsigned c   = (unsigned)e / NBINS;
        unsigned bin = (unsigned)e - c * NBINS;
        out[obase + e] = lds[bin * 65 + c];    // bank-conflict-free
    }
}

extern "C" void kernel_launch(void* const* d_in, const int* in_sizes, int n_in,
                              void* d_out, int out_size, void* d_ws, size_t ws_size,
                              hipStream_t stream) {
    const float* feat  = (const float*)d_in[0];
    const float* boxes = (const float*)d_in[1];
    const int* im_sz   = (const int*)d_in[2];
    float* out   = (float*)d_out;
    float* featT = (float*)d_ws;    // 2.56 MB of ~256 MB scratch

    transpose_kernel<<<160, 256, 0, stream>>>(feat, featT);
    pool_kernel<<<RN * 4, 256, 0, stream>>>(featT, boxes, im_sz, out);
}